// Round 11
// baseline (763.712 us; speedup 1.0000x reference)
//
#include <hip/hip_runtime.h>

typedef unsigned int u32;
typedef unsigned short u16;
typedef __bf16 bf16x8 __attribute__((ext_vector_type(8)));
typedef float f32x4 __attribute__((ext_vector_type(4)));
typedef u32 u32x4 __attribute__((ext_vector_type(4)));
typedef u32 u32x2 __attribute__((ext_vector_type(2)));

#define NTOK 64
#define CDIM 256
#define NH 8

// ---- workspace layout (u16 units, after 16-byte flag header) ----
#define WS_HDR 8
#define BIAS_O (WS_HDR)             // [8][n 64][m 64] expanded bias (32768)
#define WQKV_O (BIAS_O + 32768)     // w_qkv bf16                    (196608)
#define BQKV_O (WQKV_O + 196608)    // b_qkv bf16                    (768)
#define WPRJ_O (BQKV_O + 768)       // w_proj bf16                   (65536)
#define BPRJ_O (WPRJ_O + 65536)     // b_proj bf16                   (256)

// ---- LDS: x tile [64][520B] = 33,280 B; reused as y tile after B2 ----
#define XROW 520
#define LDS_BYTES 33280

__device__ __forceinline__ float bf2f(u16 u) {
  union { u32 i; float f; } z; z.i = ((u32)u) << 16; return z.f;
}
__device__ __forceinline__ u16 f2bf(float f) {
  __bf16 h = (__bf16)f; return __builtin_bit_cast(u16, h);
}
__device__ __forceinline__ u32 pk2(float a, float b) {
  return (u32)f2bf(a) | ((u32)f2bf(b) << 16);
}
__device__ __forceinline__ float fetchf(const void* p, int idx, int isbf) {
  return isbf ? bf2f(((const u16*)p)[idx]) : ((const float*)p)[idx];
}

// Universal acc->frag repack (HW-verified rounds 6-10).
__device__ __forceinline__ bf16x8 frag_from(u32 p00, u32 p01, u32 p10, u32 p11,
                                            int s0, int s1, bool hi) {
  u32 A0 = (u32)__shfl((int)p00, s0, 64);
  u32 A1 = (u32)__shfl((int)p01, s0, 64);
  u32 B0 = (u32)__shfl((int)p10, s0, 64);
  u32 B1 = (u32)__shfl((int)p11, s0, 64);
  u32 C0 = (u32)__shfl((int)p00, s1, 64);
  u32 C1 = (u32)__shfl((int)p01, s1, 64);
  u32 D0 = (u32)__shfl((int)p10, s1, 64);
  u32 D1 = (u32)__shfl((int)p11, s1, 64);
  u32x4 f;
  f[0] = hi ? B0 : A0;  f[1] = hi ? B1 : A1;
  f[2] = hi ? D0 : C0;  f[3] = hi ? D1 : C1;
  return __builtin_bit_cast(bf16x8, f);
}

__global__ void detect_dtype(const u16* __restrict__ x, int* __restrict__ flag) {
  __shared__ int cnt;
  if (threadIdx.x == 0) cnt = 0;
  __syncthreads();
  int sane = 0;
  for (int i = threadIdx.x; i < 2048; i += 256) {
    u16 u = x[2 * i];
    int e = (u >> 7) & 0xFF;
    sane += (e == 0 || (e >= 90 && e <= 160)) ? 1 : 0;
  }
  atomicAdd(&cnt, sane);
  __syncthreads();
  if (threadIdx.x == 0) *flag = (cnt >= 1638) ? 1 : 0;
}

// bias expanded to [h][n][m]
__global__ void cvt_params(const void* __restrict__ wqkv, const void* __restrict__ bqkv,
                           const void* __restrict__ btab, const void* __restrict__ wprj,
                           const void* __restrict__ bprj, void* __restrict__ wsraw) {
  u16* ws = (u16*)wsraw;
  const int isbf = *(const int*)wsraw;
  int i = blockIdx.x * 256 + threadIdx.x;
  if (i < 32768) {
    int n = (i >> 6) & 63, m = i & 63, h = i >> 12;
    int r0 = (n >> 3) - (m >> 3) + 7, r1 = (n & 7) - (m & 7) + 7;
    ws[BIAS_O + i] = f2bf(fetchf(btab, (r0 * 15 + r1) * NH + h, isbf));
  } else if (i < 32768 + 196608) {
    int j = i - 32768;
    ws[WQKV_O + j] = f2bf(fetchf(wqkv, j, isbf));
  } else if (i < 32768 + 196608 + 768) {
    int j = i - (32768 + 196608);
    ws[BQKV_O + j] = f2bf(fetchf(bqkv, j, isbf));
  } else if (i < 32768 + 196608 + 768 + 65536) {
    int j = i - (32768 + 196608 + 768);
    ws[WPRJ_O + j] = f2bf(fetchf(wprj, j, isbf));
  } else if (i < 32768 + 196608 + 768 + 65536 + 256) {
    int j = i - (32768 + 196608 + 768 + 65536);
    ws[BPRJ_O + j] = f2bf(fetchf(bprj, j, isbf));
  }
}

// Transposed qkv ch-tile: acc rows = channels CHB+4g+reg, cols = tokens 16nt+c.
#define TILE_T(PK, CHT, CHB, SCL) {                                                   \
    bf16x8 wf[8];                                                                     \
    const u16* wrow = ws + WQKV_O + ((CHB) + c) * CDIM;                               \
    _Pragma("unroll")                                                                 \
    for (int ks = 0; ks < 8; ++ks) wf[ks] = *(const bf16x8*)(wrow + ks * 32 + g * 8); \
    f32x4 binit;                                                                      \
    { u32x2 bp = *(const u32x2*)(ws + BQKV_O + (CHB) + 4 * g);                        \
      binit[0] = bf2f((u16)(bp[0] & 0xffff)); binit[1] = bf2f((u16)(bp[0] >> 16));    \
      binit[2] = bf2f((u16)(bp[1] & 0xffff)); binit[3] = bf2f((u16)(bp[1] >> 16)); }  \
    _Pragma("unroll")                                                                 \
    for (int nt = 0; nt < 4; ++nt) {                                                  \
      f32x4 acc = binit;                                                              \
      _Pragma("unroll")                                                               \
      for (int ks = 0; ks < 8; ++ks) {                                                \
        bf16x8 xf = *(const bf16x8*)(lds + (16 * nt + c) * XROW + ks * 64 + g * 16);  \
        acc = __builtin_amdgcn_mfma_f32_16x16x32_bf16(wf[ks], xf, acc, 0, 0, 0);      \
      }                                                                               \
      PK[CHT][nt][0] = pk2(acc[0] * (SCL), acc[1] * (SCL));                           \
      PK[CHT][nt][1] = pk2(acc[2] * (SCL), acc[3] * (SCL));                           \
    } }

// Normal qkv ch-tile (v): acc rows = tokens 16nt+4g+reg, col = channel CHB+c.
#define TILE_N(PK, CHT, CHB) {                                                        \
    bf16x8 wf[8];                                                                     \
    const u16* wrow = ws + WQKV_O + ((CHB) + c) * CDIM;                               \
    _Pragma("unroll")                                                                 \
    for (int ks = 0; ks < 8; ++ks) wf[ks] = *(const bf16x8*)(wrow + ks * 32 + g * 8); \
    const float badd = bf2f(ws[BQKV_O + (CHB) + c]);                                  \
    _Pragma("unroll")                                                                 \
    for (int nt = 0; nt < 4; ++nt) {                                                  \
      f32x4 acc = {badd, badd, badd, badd};                                           \
      _Pragma("unroll")                                                               \
      for (int ks = 0; ks < 8; ++ks) {                                                \
        bf16x8 xf = *(const bf16x8*)(lds + (16 * nt + c) * XROW + ks * 64 + g * 16);  \
        acc = __builtin_amdgcn_mfma_f32_16x16x32_bf16(xf, wf[ks], acc, 0, 0, 0);      \
      }                                                                               \
      PK[CHT][nt][0] = pk2(acc[0], acc[1]);                                           \
      PK[CHT][nt][1] = pk2(acc[2], acc[3]);                                           \
    } }

// Full stage-1 for head H: q,k transposed + v normal, then v->bvf, k->bkf.
#define STAGE1_HEAD(H) {                                                              \
    u32 vpk[2][4][2];                                                                 \
    TILE_T(qpk, 0, 32 * (H),            scale);                                       \
    TILE_T(qpk, 1, 32 * (H) + 16,       scale);                                       \
    TILE_T(kpk, 0, 256 + 32 * (H),      1.0f);                                        \
    TILE_T(kpk, 1, 256 + 32 * (H) + 16, 1.0f);                                        \
    TILE_N(vpk, 0, 512 + 32 * (H));                                                   \
    TILE_N(vpk, 1, 512 + 32 * (H) + 16);                                              \
    _Pragma("unroll")                                                                 \
    for (int dt = 0; dt < 2; ++dt)                                                    \
      _Pragma("unroll")                                                               \
      for (int k2 = 0; k2 < 2; ++k2)                                                  \
        bvf[dt][k2] = frag_from(vpk[dt][2 * k2][0], vpk[dt][2 * k2][1],               \
                                vpk[dt][2 * k2 + 1][0], vpk[dt][2 * k2 + 1][1],       \
                                s0, s1, hi);                                          \
    _Pragma("unroll")                                                                 \
    for (int mt = 0; mt < 4; ++mt)                                                    \
      bkf[mt] = frag_from(kpk[0][mt][0], kpk[0][mt][1], kpk[1][mt][0], kpk[1][mt][1], \
                          s0, s1, hi); }

// Fused per-nt attention for head H. SINK(nt, o2) consumes the 2 d-tiles.
#define ATTN_HEAD(H, SINK) {                                                          \
    _Pragma("unroll")                                                                 \
    for (int nt = 0; nt < 4; ++nt) {                                                  \
      bf16x8 aqf = frag_from(qpk[0][nt][0], qpk[0][nt][1], qpk[1][nt][0],             \
                             qpk[1][nt][1], s0, s1, hi);                              \
      f32x4 st[4];                                                                    \
      _Pragma("unroll")                                                               \
      for (int mt = 0; mt < 4; ++mt) {                                                \
        u32x2 bp = *(const u32x2*)(ws + BIAS_O + ((H) << 12) +                        \
                                   ((16 * nt + c) << 6) + 16 * mt + 4 * g);           \
        st[mt][0] = bf2f((u16)(bp[0] & 0xffff)); st[mt][1] = bf2f((u16)(bp[0] >> 16));\
        st[mt][2] = bf2f((u16)(bp[1] & 0xffff)); st[mt][3] = bf2f((u16)(bp[1] >> 16));\
      }                                                                               \
      _Pragma("unroll")                                                               \
      for (int mt = 0; mt < 4; ++mt)                                                  \
        st[mt] = __builtin_amdgcn_mfma_f32_16x16x32_bf16(bkf[mt], aqf, st[mt], 0,0,0);\
      float mx = st[0][0];                                                            \
      _Pragma("unroll")                                                               \
      for (int mt = 0; mt < 4; ++mt)                                                  \
        _Pragma("unroll")                                                             \
        for (int r = 0; r < 4; ++r) mx = fmaxf(mx, st[mt][r]);                        \
      mx = fmaxf(mx, __shfl_xor(mx, 16));                                             \
      mx = fmaxf(mx, __shfl_xor(mx, 32));                                             \
      float sum = 0.f;                                                                \
      _Pragma("unroll")                                                               \
      for (int mt = 0; mt < 4; ++mt)                                                  \
        _Pragma("unroll")                                                             \
        for (int r = 0; r < 4; ++r) { float e = __expf(st[mt][r] - mx);               \
                                      st[mt][r] = e; sum += e; }                      \
      sum += __shfl_xor(sum, 16);                                                     \
      sum += __shfl_xor(sum, 32);                                                     \
      float inv = 1.0f / sum;                                                         \
      u32 pp[4][2];                                                                   \
      _Pragma("unroll")                                                               \
      for (int mt = 0; mt < 4; ++mt) {                                                \
        pp[mt][0] = pk2(st[mt][0] * inv, st[mt][1] * inv);                            \
        pp[mt][1] = pk2(st[mt][2] * inv, st[mt][3] * inv);                            \
      }                                                                               \
      f32x4 o2[2] = {{0,0,0,0},{0,0,0,0}};                                            \
      _Pragma("unroll")                                                               \
      for (int k2 = 0; k2 < 2; ++k2) {                                                \
        bf16x8 paf = frag_from(pp[2 * k2][0], pp[2 * k2][1],                          \
                               pp[2 * k2 + 1][0], pp[2 * k2 + 1][1], s0, s1, hi);     \
        o2[0] = __builtin_amdgcn_mfma_f32_16x16x32_bf16(paf, bvf[0][k2], o2[0],0,0,0);\
        o2[1] = __builtin_amdgcn_mfma_f32_16x16x32_bf16(paf, bvf[1][k2], o2[1],0,0,0);\
      }                                                                               \
      SINK(nt, o2);                                                                   \
    } }

// head0: park packed y in 16 regs (x-LDS still live for head1's stage 1)
#define SINK_PARK(NT, O2) {                                                           \
    yp0[NT][0][0] = pk2(O2[0][0], O2[0][1]);                                          \
    yp0[NT][0][1] = pk2(O2[0][2], O2[0][3]);                                          \
    yp0[NT][1][0] = pk2(O2[1][0], O2[1][1]);                                          \
    yp0[NT][1][1] = pk2(O2[1][2], O2[1][3]); }

// head1 (post-B2): write y rows directly to LDS
#define SINK_LDS(NT, O2) {                                                            \
    _Pragma("unroll")                                                                 \
    for (int dt = 0; dt < 2; ++dt)                                                    \
      _Pragma("unroll")                                                               \
      for (int r = 0; r < 4; ++r) {                                                   \
        int n = 16 * (NT) + 4 * g + r, col = 32 * h1 + 16 * dt + c;                   \
        *(u16*)(lds + n * XROW + col * 2) = f2bf(O2[dt][r]);                          \
      } }

// 256-thr blocks (4 waves): occupancy moves in 1-wave/SIMD steps (512-thr
// quantizes in 2-wave steps -> the r8-r10 trap). Cap 512/3=170 unified: actual
// usage was 172 under a lax cap; nominal peak of this structure ~140 -> fits.
__global__ __launch_bounds__(256, 3)
void win_attn_fused(const void* __restrict__ xraw, const void* __restrict__ wsraw,
                    float* __restrict__ out)
{
  __shared__ __align__(16) unsigned char lds[LDS_BYTES];
  const u16* ws  = (const u16*)wsraw;
  const int isbf = *(const int*)wsraw;
  const int b    = blockIdx.x;
  const int tid  = threadIdx.x;
  const int w    = tid >> 6;     // wave id 0..3; handles heads w and w+4
  const int lane = tid & 63;
  const int c    = lane & 15;
  const int g    = lane >> 4;
  const float scale = 0.1767766952966369f;  // 32^-0.5

  // ---- stage 0: x[b] (64x256) -> LDS bf16 [64][520B]
  if (isbf) {
    const u32x4* gx = (const u32x4*)((const u16*)xraw + (size_t)b * (NTOK * CDIM));
#pragma unroll
    for (int i = 0; i < 8; ++i) {
      int q = tid + i * 256;
      int row = q >> 5, c8 = q & 31;
      *(u32x4*)(lds + row * XROW + c8 * 16) = gx[q];
    }
  } else {
    const f32x4* gx = (const f32x4*)((const float*)xraw + (size_t)b * (NTOK * CDIM));
#pragma unroll
    for (int i = 0; i < 16; ++i) {
      int q = tid + i * 256;
      int row = q >> 6, c4 = q & 63;
      f32x4 v = gx[q];
      u32x2 pkv;
      pkv[0] = pk2(v[0], v[1]);
      pkv[1] = pk2(v[2], v[3]);
      *(u32x2*)(lds + row * XROW + c4 * 8) = pkv;
    }
  }
  __syncthreads();   // B1

  const int s0 = c + 32 * (g & 1), s1 = s0 + 16;
  const bool hi = ((g >> 1) & 1) != 0;
  const int h0 = w, h1 = w + 4;

  u32 qpk[2][4][2], kpk[2][4][2];
  bf16x8 bvf[2][2], bkf[4];
  u32 yp0[4][2][2];

  // ---- head h0: stage1 + attention, y parked in regs (x must stay live)
  STAGE1_HEAD(h0);
  ATTN_HEAD(h0, SINK_PARK);

  // ---- head h1: stage1 (last x reads)
  STAGE1_HEAD(h1);
  __syncthreads();   // B2: x-LDS dead -> y overlay region open

  // ---- head h1 attention -> y direct; unpark head h0's y
  ATTN_HEAD(h1, SINK_LDS);
#pragma unroll
  for (int nt = 0; nt < 4; ++nt)
#pragma unroll
    for (int dt = 0; dt < 2; ++dt) {
      int col = 32 * h0 + 16 * dt + c;
      int n0 = 16 * nt + 4 * g;
      *(u16*)(lds + (n0 + 0) * XROW + col * 2) = (u16)(yp0[nt][dt][0] & 0xffff);
      *(u16*)(lds + (n0 + 1) * XROW + col * 2) = (u16)(yp0[nt][dt][0] >> 16);
      *(u16*)(lds + (n0 + 2) * XROW + col * 2) = (u16)(yp0[nt][dt][1] & 0xffff);
      *(u16*)(lds + (n0 + 3) * XROW + col * 2) = (u16)(yp0[nt][dt][1] >> 16);
    }
  __syncthreads();   // B3: y complete

  // ---- proj: 4 col-tiles per wave; ay inline (LDS reads are cheap, r9 A/B)
  float* gout = out + (size_t)b * (NTOK * CDIM);
#pragma unroll
  for (int ct = 0; ct < 4; ++ct) {
    const int colw = 64 * w + 16 * ct + c;
    const float badd = bf2f(ws[BPRJ_O + colw]);
    f32x4 acc[4];
#pragma unroll
    for (int rt = 0; rt < 4; ++rt)
#pragma unroll
      for (int r = 0; r < 4; ++r) acc[rt][r] = badd;
    const u16* wrow = ws + WPRJ_O + colw * CDIM;
#pragma unroll
    for (int ks = 0; ks < 8; ++ks) {
      bf16x8 wf = *(const bf16x8*)(wrow + ks * 32 + g * 8);
#pragma unroll
      for (int rt = 0; rt < 4; ++rt) {
        bf16x8 ay = *(const bf16x8*)(lds + (16 * rt + c) * XROW + ks * 64 + g * 16);
        acc[rt] = __builtin_amdgcn_mfma_f32_16x16x32_bf16(ay, wf, acc[rt], 0, 0, 0);
      }
    }
#pragma unroll
    for (int rt = 0; rt < 4; ++rt)
#pragma unroll
      for (int r = 0; r < 4; ++r) {
        int n = 16 * rt + 4 * g + r;
        gout[n * CDIM + colw] = acc[rt][r];
      }
  }
}

extern "C" void kernel_launch(void* const* d_in, const int* in_sizes, int n_in,
                              void* d_out, int out_size, void* d_ws, size_t ws_size,
                              hipStream_t stream) {
  (void)in_sizes; (void)n_in; (void)out_size; (void)ws_size;
  detect_dtype<<<dim3(1), dim3(256), 0, stream>>>((const u16*)d_in[0], (int*)d_ws);
  cvt_params<<<dim3(1156), dim3(256), 0, stream>>>(d_in[1], d_in[2], d_in[3], d_in[4],
                                                   d_in[5], d_ws);
  win_attn_fused<<<dim3(4096), dim3(256), 0, stream>>>(d_in[0], d_ws, (float*)d_out);
}

// Round 12
// 495.340 us; speedup vs baseline: 1.5418x; 1.5418x over previous
//
#include <hip/hip_runtime.h>

typedef unsigned int u32;
typedef unsigned short u16;
typedef __bf16 bf16x8 __attribute__((ext_vector_type(8)));
typedef float f32x4 __attribute__((ext_vector_type(4)));
typedef u32 u32x4 __attribute__((ext_vector_type(4)));
typedef u32 u32x2 __attribute__((ext_vector_type(2)));

#define NTOK 64
#define CDIM 256
#define NH 8

// ---- workspace layout (u16 units, after 16-byte flag header) ----
#define WS_HDR 8
#define BIAS_O (WS_HDR)             // [8][n 64][m 64] expanded bias (32768)
#define WQKV_O (BIAS_O + 32768)     // w_qkv bf16                    (196608)
#define BQKV_O (WQKV_O + 196608)    // b_qkv bf16                    (768)
#define WPRJ_O (BQKV_O + 768)       // w_proj bf16                   (65536)
#define BPRJ_O (WPRJ_O + 65536)     // b_proj bf16                   (256)

// ---- LDS: x tile [64][520B] = 33,280 B; reused as y tile after B2 ----
#define XROW 520
#define LDS_BYTES 33280

__device__ __forceinline__ float bf2f(u16 u) {
  union { u32 i; float f; } z; z.i = ((u32)u) << 16; return z.f;
}
__device__ __forceinline__ u16 f2bf(float f) {
  __bf16 h = (__bf16)f; return __builtin_bit_cast(u16, h);
}
__device__ __forceinline__ u32 pk2(float a, float b) {
  return (u32)f2bf(a) | ((u32)f2bf(b) << 16);
}
__device__ __forceinline__ float fetchf(const void* p, int idx, int isbf) {
  return isbf ? bf2f(((const u16*)p)[idx]) : ((const float*)p)[idx];
}

// Universal acc->frag repack (HW-verified rounds 6-11).
__device__ __forceinline__ bf16x8 frag_from(u32 p00, u32 p01, u32 p10, u32 p11,
                                            int s0, int s1, bool hi) {
  u32 A0 = (u32)__shfl((int)p00, s0, 64);
  u32 A1 = (u32)__shfl((int)p01, s0, 64);
  u32 B0 = (u32)__shfl((int)p10, s0, 64);
  u32 B1 = (u32)__shfl((int)p11, s0, 64);
  u32 C0 = (u32)__shfl((int)p00, s1, 64);
  u32 C1 = (u32)__shfl((int)p01, s1, 64);
  u32 D0 = (u32)__shfl((int)p10, s1, 64);
  u32 D1 = (u32)__shfl((int)p11, s1, 64);
  u32x4 f;
  f[0] = hi ? B0 : A0;  f[1] = hi ? B1 : A1;
  f[2] = hi ? D0 : C0;  f[3] = hi ? D1 : C1;
  return __builtin_bit_cast(bf16x8, f);
}

__global__ void detect_dtype(const u16* __restrict__ x, int* __restrict__ flag) {
  __shared__ int cnt;
  if (threadIdx.x == 0) cnt = 0;
  __syncthreads();
  int sane = 0;
  for (int i = threadIdx.x; i < 2048; i += 256) {
    u16 u = x[2 * i];
    int e = (u >> 7) & 0xFF;
    sane += (e == 0 || (e >= 90 && e <= 160)) ? 1 : 0;
  }
  atomicAdd(&cnt, sane);
  __syncthreads();
  if (threadIdx.x == 0) *flag = (cnt >= 1638) ? 1 : 0;
}

// bias expanded to [h][n][m]
__global__ void cvt_params(const void* __restrict__ wqkv, const void* __restrict__ bqkv,
                           const void* __restrict__ btab, const void* __restrict__ wprj,
                           const void* __restrict__ bprj, void* __restrict__ wsraw) {
  u16* ws = (u16*)wsraw;
  const int isbf = *(const int*)wsraw;
  int i = blockIdx.x * 256 + threadIdx.x;
  if (i < 32768) {
    int n = (i >> 6) & 63, m = i & 63, h = i >> 12;
    int r0 = (n >> 3) - (m >> 3) + 7, r1 = (n & 7) - (m & 7) + 7;
    ws[BIAS_O + i] = f2bf(fetchf(btab, (r0 * 15 + r1) * NH + h, isbf));
  } else if (i < 32768 + 196608) {
    int j = i - 32768;
    ws[WQKV_O + j] = f2bf(fetchf(wqkv, j, isbf));
  } else if (i < 32768 + 196608 + 768) {
    int j = i - (32768 + 196608);
    ws[BQKV_O + j] = f2bf(fetchf(bqkv, j, isbf));
  } else if (i < 32768 + 196608 + 768 + 65536) {
    int j = i - (32768 + 196608 + 768);
    ws[WPRJ_O + j] = f2bf(fetchf(wprj, j, isbf));
  } else if (i < 32768 + 196608 + 768 + 65536 + 256) {
    int j = i - (32768 + 196608 + 768 + 65536);
    ws[BPRJ_O + j] = f2bf(fetchf(bprj, j, isbf));
  }
}

// Transposed qkv ch-tile: acc rows = channels CHB+4g+reg, cols = tokens 16nt+c.
#define TILE_T(PK, CHT, CHB, SCL) {                                                   \
    bf16x8 wf[8];                                                                     \
    const u16* wrow = ws + WQKV_O + ((CHB) + c) * CDIM;                               \
    _Pragma("unroll")                                                                 \
    for (int ks = 0; ks < 8; ++ks) wf[ks] = *(const bf16x8*)(wrow + ks * 32 + g * 8); \
    f32x4 binit;                                                                      \
    { u32x2 bp = *(const u32x2*)(ws + BQKV_O + (CHB) + 4 * g);                        \
      binit[0] = bf2f((u16)(bp[0] & 0xffff)); binit[1] = bf2f((u16)(bp[0] >> 16));    \
      binit[2] = bf2f((u16)(bp[1] & 0xffff)); binit[3] = bf2f((u16)(bp[1] >> 16)); }  \
    _Pragma("unroll")                                                                 \
    for (int nt = 0; nt < 4; ++nt) {                                                  \
      f32x4 acc = binit;                                                              \
      _Pragma("unroll")                                                               \
      for (int ks = 0; ks < 8; ++ks) {                                                \
        bf16x8 xf = *(const bf16x8*)(lds + (16 * nt + c) * XROW + ks * 64 + g * 16);  \
        acc = __builtin_amdgcn_mfma_f32_16x16x32_bf16(wf[ks], xf, acc, 0, 0, 0);      \
      }                                                                               \
      PK[CHT][nt][0] = pk2(acc[0] * (SCL), acc[1] * (SCL));                           \
      PK[CHT][nt][1] = pk2(acc[2] * (SCL), acc[3] * (SCL));                           \
    } }

// Normal qkv ch-tile (v): acc rows = tokens 16nt+4g+reg, col = channel CHB+c.
#define TILE_N(PK, CHT, CHB) {                                                        \
    bf16x8 wf[8];                                                                     \
    const u16* wrow = ws + WQKV_O + ((CHB) + c) * CDIM;                               \
    _Pragma("unroll")                                                                 \
    for (int ks = 0; ks < 8; ++ks) wf[ks] = *(const bf16x8*)(wrow + ks * 32 + g * 8); \
    const float badd = bf2f(ws[BQKV_O + (CHB) + c]);                                  \
    _Pragma("unroll")                                                                 \
    for (int nt = 0; nt < 4; ++nt) {                                                  \
      f32x4 acc = {badd, badd, badd, badd};                                           \
      _Pragma("unroll")                                                               \
      for (int ks = 0; ks < 8; ++ks) {                                                \
        bf16x8 xf = *(const bf16x8*)(lds + (16 * nt + c) * XROW + ks * 64 + g * 16);  \
        acc = __builtin_amdgcn_mfma_f32_16x16x32_bf16(xf, wf[ks], acc, 0, 0, 0);      \
      }                                                                               \
      PK[CHT][nt][0] = pk2(acc[0], acc[1]);                                           \
      PK[CHT][nt][1] = pk2(acc[2], acc[3]);                                           \
    } }

// launch_bounds(512,3): unified cap = 512/3 = 170. r8 measured ~172 total under
// a lax cap; THIS fused structure (per-nt softmax/PV, no resident Ppk/o) peaks
// ~130-160 -> fits 170 without spill (r10's cap 128 was 40+ regs short -> spill;
// r11's two-head state was 50+ regs over -> spill). Target: 3 waves/SIMD.
__global__ __launch_bounds__(512, 3)
void win_attn_fused(const void* __restrict__ xraw, const void* __restrict__ wsraw,
                    float* __restrict__ out)
{
  __shared__ __align__(16) unsigned char lds[LDS_BYTES];
  const u16* ws  = (const u16*)wsraw;
  const int isbf = *(const int*)wsraw;
  const int b    = blockIdx.x;
  const int tid  = threadIdx.x;
  const int w    = tid >> 6;     // wave id = head id
  const int lane = tid & 63;
  const int c    = lane & 15;
  const int g    = lane >> 4;
  const float scale = 0.1767766952966369f;  // 32^-0.5

  // ---- stage 0: x[b] (64x256) -> LDS bf16 [64][520B]
  if (isbf) {
    const u32x4* gx = (const u32x4*)((const u16*)xraw + (size_t)b * (NTOK * CDIM));
#pragma unroll
    for (int i = 0; i < 4; ++i) {
      int q = tid + i * 512;
      int row = q >> 5, c8 = q & 31;
      *(u32x4*)(lds + row * XROW + c8 * 16) = gx[q];
    }
  } else {
    const f32x4* gx = (const f32x4*)((const float*)xraw + (size_t)b * (NTOK * CDIM));
#pragma unroll
    for (int i = 0; i < 8; ++i) {
      int q = tid + i * 512;
      int row = q >> 6, c4 = q & 63;
      f32x4 v = gx[q];
      u32x2 pkv;
      pkv[0] = pk2(v[0], v[1]);
      pkv[1] = pk2(v[2], v[3]);
      *(u32x2*)(lds + row * XROW + c4 * 8) = pkv;
    }
  }
  __syncthreads();   // B1

  const int s0 = c + 32 * (g & 1), s1 = s0 + 16;
  const bool hi = ((g >> 1) & 1) != 0;
  const int h = w;

  // ---- stage 1: per-head q,k (transposed) and v (normal), packed in registers
  u32 qpk[2][4][2], kpk[2][4][2];
  bf16x8 bvf[2][2];
  TILE_T(qpk, 0, 32 * w,            scale);
  TILE_T(qpk, 1, 32 * w + 16,       scale);
  TILE_T(kpk, 0, 256 + 32 * w,      1.0f);
  TILE_T(kpk, 1, 256 + 32 * w + 16, 1.0f);
  {
    u32 vpk[2][4][2];
    TILE_N(vpk, 0, 512 + 32 * w);
    TILE_N(vpk, 1, 512 + 32 * w + 16);
    // convert v -> B-frags NOW (frees vpk before the attention phase)
#pragma unroll
    for (int dt = 0; dt < 2; ++dt)
#pragma unroll
      for (int k2 = 0; k2 < 2; ++k2)
        bvf[dt][k2] = frag_from(vpk[dt][2 * k2][0], vpk[dt][2 * k2][1],
                                vpk[dt][2 * k2 + 1][0], vpk[dt][2 * k2 + 1][1], s0, s1, hi);
  }
  __syncthreads();   // B2: x-LDS dead; region holds y below

  // ---- k -> A-frags (kpk dies here)
  bf16x8 bkf[4];
#pragma unroll
  for (int mt = 0; mt < 4; ++mt)
    bkf[mt] = frag_from(kpk[0][mt][0], kpk[0][mt][1], kpk[1][mt][0], kpk[1][mt][1], s0, s1, hi);

  // ---- FUSED per-nt: S^T col-strip -> softmax -> PV -> y-write.
  // P and o never fully resident (pp[4][2]=8, o2[2]=8 regs transient per nt).
#pragma unroll
  for (int nt = 0; nt < 4; ++nt) {
    bf16x8 aqf = frag_from(qpk[0][nt][0], qpk[0][nt][1], qpk[1][nt][0], qpk[1][nt][1], s0, s1, hi);
    f32x4 st[4];
#pragma unroll
    for (int mt = 0; mt < 4; ++mt) {
      u32x2 bp = *(const u32x2*)(ws + BIAS_O + (h << 12) + ((16 * nt + c) << 6) + 16 * mt + 4 * g);
      st[mt][0] = bf2f((u16)(bp[0] & 0xffff)); st[mt][1] = bf2f((u16)(bp[0] >> 16));
      st[mt][2] = bf2f((u16)(bp[1] & 0xffff)); st[mt][3] = bf2f((u16)(bp[1] >> 16));
    }
#pragma unroll
    for (int mt = 0; mt < 4; ++mt)
      st[mt] = __builtin_amdgcn_mfma_f32_16x16x32_bf16(bkf[mt], aqf, st[mt], 0, 0, 0);
    float mx = st[0][0];
#pragma unroll
    for (int mt = 0; mt < 4; ++mt)
#pragma unroll
      for (int r = 0; r < 4; ++r) mx = fmaxf(mx, st[mt][r]);
    mx = fmaxf(mx, __shfl_xor(mx, 16));
    mx = fmaxf(mx, __shfl_xor(mx, 32));
    float sum = 0.f;
#pragma unroll
    for (int mt = 0; mt < 4; ++mt)
#pragma unroll
      for (int r = 0; r < 4; ++r) { float e = __expf(st[mt][r] - mx); st[mt][r] = e; sum += e; }
    sum += __shfl_xor(sum, 16);
    sum += __shfl_xor(sum, 32);
    float inv = 1.0f / sum;
    u32 pp[4][2];
#pragma unroll
    for (int mt = 0; mt < 4; ++mt) {
      pp[mt][0] = pk2(st[mt][0] * inv, st[mt][1] * inv);
      pp[mt][1] = pk2(st[mt][2] * inv, st[mt][3] * inv);
    }
    f32x4 o2[2] = {{0,0,0,0},{0,0,0,0}};
#pragma unroll
    for (int k2 = 0; k2 < 2; ++k2) {
      bf16x8 paf = frag_from(pp[2 * k2][0], pp[2 * k2][1],
                             pp[2 * k2 + 1][0], pp[2 * k2 + 1][1], s0, s1, hi);
      o2[0] = __builtin_amdgcn_mfma_f32_16x16x32_bf16(paf, bvf[0][k2], o2[0], 0, 0, 0);
      o2[1] = __builtin_amdgcn_mfma_f32_16x16x32_bf16(paf, bvf[1][k2], o2[1], 0, 0, 0);
    }
    // y rows for this nt (x region dead since B2; disjoint per-wave cols)
#pragma unroll
    for (int dt = 0; dt < 2; ++dt)
#pragma unroll
      for (int r = 0; r < 4; ++r) {
        int n = 16 * nt + 4 * g + r, col = 32 * w + 16 * dt + c;
        *(u16*)(lds + n * XROW + col * 2) = f2bf(o2[dt][r]);
      }
  }
  __syncthreads();   // B3: y complete

  // ---- proj: out = y @ w_proj^T + b_proj ; ay inline; direct f32 scatter
  float* gout = out + (size_t)b * (NTOK * CDIM);
#pragma unroll
  for (int ct = 0; ct < 2; ++ct) {
    const int colw = 32 * w + 16 * ct + c;
    const float badd = bf2f(ws[BPRJ_O + colw]);
    f32x4 acc[4];
#pragma unroll
    for (int rt = 0; rt < 4; ++rt)
#pragma unroll
      for (int r = 0; r < 4; ++r) acc[rt][r] = badd;
    const u16* wrow = ws + WPRJ_O + colw * CDIM;
#pragma unroll
    for (int ks = 0; ks < 8; ++ks) {
      bf16x8 wf = *(const bf16x8*)(wrow + ks * 32 + g * 8);
#pragma unroll
      for (int rt = 0; rt < 4; ++rt) {
        bf16x8 ay = *(const bf16x8*)(lds + (16 * rt + c) * XROW + ks * 64 + g * 16);
        acc[rt] = __builtin_amdgcn_mfma_f32_16x16x32_bf16(ay, wf, acc[rt], 0, 0, 0);
      }
    }
#pragma unroll
    for (int rt = 0; rt < 4; ++rt)
#pragma unroll
      for (int r = 0; r < 4; ++r) {
        int n = 16 * rt + 4 * g + r;
        gout[n * CDIM + colw] = acc[rt][r];
      }
  }
}

extern "C" void kernel_launch(void* const* d_in, const int* in_sizes, int n_in,
                              void* d_out, int out_size, void* d_ws, size_t ws_size,
                              hipStream_t stream) {
  (void)in_sizes; (void)n_in; (void)out_size; (void)ws_size;
  detect_dtype<<<dim3(1), dim3(256), 0, stream>>>((const u16*)d_in[0], (int*)d_ws);
  cvt_params<<<dim3(1156), dim3(256), 0, stream>>>(d_in[1], d_in[2], d_in[3], d_in[4],
                                                   d_in[5], d_ws);
  win_attn_fused<<<dim3(4096), dim3(512), 0, stream>>>(d_in[0], d_ws, (float*)d_out);
}